// Round 5
// baseline (205.340 us; speedup 1.0000x reference)
//
#include <hip/hip_runtime.h>

typedef __bf16 bf16x8 __attribute__((ext_vector_type(8)));
typedef float  floatx16 __attribute__((ext_vector_type(16)));

#define HW   56
#define NPIX 3136
#define CIN  128
#define COUT 256

// W2 layout: [cc(4)][tap(9)][cg(4)][oc(256)][j(8)], bf16. 576 KB of d_ws.
__global__ __launch_bounds__(256) void wt_transform_kernel(
        const float* __restrict__ Kw, __bf16* __restrict__ W2) {
    int idx = blockIdx.x * 256 + threadIdx.x;     // coalesced write
    int j     = idx & 7;
    int oc    = (idx >> 3) & 255;
    int cg    = (idx >> 11) & 3;
    int tapcc = idx >> 13;                        // cc*9 + tap
    int tap   = tapcc % 9;
    int cc    = tapcc / 9;
    int c = cc * 32 + cg * 8 + j;
    W2[idx] = (__bf16)Kw[oc * 1152 + c * 9 + tap];
}

// Xs: [row(6)][wp(66)][slot(40)] bf16; slots 0..31 = ci (cg*8+j), 32..39 pad.
// Stride 40 elems = 80 B: bank-base advances 20 banks/wp -> conflict-free b128.
__device__ __forceinline__ int xs_idx(int row, int wp, int cg) {
    return row * 2640 + wp * 40 + cg * 8;
}

// R7: A (weights) from L2 straight to REGISTERS, software-pipelined 2 kc-slots
// ahead via a rotating 3-set queue (static indices, full unroll). Rationale:
// R6's accounting closed — LDS read pipe was the wall (8.3 MB/CU of b128 at
// ~85 B/cyc = 40 us of 91), with A reads half of it, plus 10 barriers/cc to
// protect shared A buffers. A-loads + consumers now live within one wave: no
// inter-wave sync for A at all (2 barriers/cc), LDS serves only B (~20 us),
// and the A stream rides the parallel VMEM/L1 pipe. The 2-slot-deep queue
// makes the compiler emit counted vmcnt(4) waits (T4 by construction) — each
// slot's loads issue ~2 slots (~300-500 cyc) before use, covering L1/L2
// latency, which is what R4 (same structure, no prefetch) was missing.
// Regs: 24 A-queue + 8 B + 64 acc + misc ~= 121; launch_bounds pins <= 128.
__global__ __launch_bounds__(512, 4) void conv_kernel(
        const float* __restrict__ x, const __bf16* __restrict__ W2,
        const float* __restrict__ bias, float* __restrict__ out) {
    __shared__ __align__(16) __bf16 Xs[6 * 2640];   // 31.7 KB, 2 blocks/CU (reg-bound)

    const int t    = threadIdx.x;
    const int nb   = blockIdx.x / 14;
    const int ht   = blockIdx.x % 14;
    const int h0   = ht * 4;
    const int ocb  = blockIdx.y * 128;

    const int wid  = t >> 6;          // 0..7
    const int lane = t & 63;
    const int half = lane >> 5;
    const int l31  = lane & 31;

    const int oc_rel = (wid & 1) * 64;          // wave's 64-oc slice within block
    const int prow   = wid >> 1;                // wave's output row (0..3)

    // Lane's A base: folds half and oc. Per-(cc,tap,kc,mi) offsets are affine:
    // elem = (cc*9+tap)*8192 + (kc*2+half)*2048 + (ocb+oc_rel+l31+mi*32)*8.
    const __bf16* wlane = W2 + half * 2048 + (size_t)(ocb + oc_rel + l31) * 8;

    floatx16 acc[2][2];
    #pragma unroll
    for (int mi = 0; mi < 2; ++mi)
        #pragma unroll
        for (int nj = 0; nj < 2; ++nj)
            #pragma unroll
            for (int k = 0; k < 16; ++k)
                acc[mi][nj][k] = 0.f;

    // Zero halo columns wp==0 and wp in [57,66): 6 rows x 10 wp x 4 cg = 240.
    if (t < 240) {
        int cg   = t & 3;
        int rest = t >> 2;            // 0..59
        int row  = rest / 10;
        int zw   = rest % 10;
        int wp   = (zw == 0) ? 0 : (56 + zw);
        *(int4*)&Xs[xs_idx(row, wp, cg)] = make_int4(0, 0, 0, 0);
    }

    // Staging map: t -> (w = t&63, cg = (t>>6)&3, rowgroup = t>>8).
    const int  sw     = t & 63;
    const int  sgr    = t >> 6;       // 0..7
    const int  sg     = sgr & 3;      // cg, uniform per wave -> clean b128 writes
    const int  rg2    = sgr >> 2;     // 0/1 row-group
    const bool wvalid = sw < 56;

    // Rotating A queue: 3 kc-slot sets x 2 mi fragments. All indices static.
    bf16x8 aq[3][2];

    for (int cc = 0; cc < 4; ++cc) {
        const __bf16* wcc = wlane + (size_t)cc * 73728;   // cc*9*8192 elems

        __syncthreads();              // protect Xs against overwrite
        // Prefetch A slots 0,1 (tap0/kc0, tap0/kc1) BEFORE staging loads:
        // issued first -> complete long before the barrier drains staging.
        #pragma unroll
        for (int mi = 0; mi < 2; ++mi) {
            aq[0][mi] = *(const bf16x8*)(wcc + 0 * 4096 + mi * 256);
            aq[1][mi] = *(const bf16x8*)(wcc + 1 * 4096 + mi * 256);
        }
        #pragma unroll
        for (int p = 0; p < 3; ++p) {
            int row = rg2 * 3 + p;    // rows 0..2 / 3..5
            int hin = h0 - 1 + row;
            bf16x8 v;
            #pragma unroll
            for (int j = 0; j < 8; ++j) v[j] = (__bf16)0.f;
            if (wvalid && (unsigned)hin < 56u) {
                const float* src = x + (size_t)(nb * CIN + cc * 32 + sg * 8) * NPIX
                                     + hin * HW + sw;
                #pragma unroll
                for (int j = 0; j < 8; ++j)
                    v[j] = (__bf16)src[j * NPIX];   // coalesced across lanes
            }
            if (wvalid)
                *(bf16x8*)&Xs[xs_idx(row, 1 + sw, sg)] = v;   // one ds_write_b128
        }
        __syncthreads();

        // 18 kc-slots (9 taps x 2 kc), barrier-free. Slot s computes with
        // aq[s%3] while slot s+2 loads into aq[(s+2)%3] (clobbers the set
        // consumed at s-1). Compiler emits vmcnt(4): 2 slots in flight.
        #pragma unroll
        for (int s = 0; s < 18; ++s) {
            const int tap = s >> 1, kc = s & 1;
            const int r = tap / 3, sx = tap % 3;
            if (s < 16) {
                const int ns = s + 2, ntap = ns >> 1, nkc = ns & 1, nq = ns % 3;
                #pragma unroll
                for (int mi = 0; mi < 2; ++mi)
                    aq[nq][mi] = *(const bf16x8*)(wcc + ntap * 8192 + nkc * 4096 + mi * 256);
            }
            bf16x8 bfr[2];
            #pragma unroll
            for (int nj = 0; nj < 2; ++nj)
                bfr[nj] = *(const bf16x8*)&Xs[xs_idx(prow + r, nj * 32 + l31 + sx,
                                                     kc * 2 + half)];
            #pragma unroll
            for (int mi = 0; mi < 2; ++mi)
                #pragma unroll
                for (int nj = 0; nj < 2; ++nj)
                    acc[mi][nj] = __builtin_amdgcn_mfma_f32_32x32x16_bf16(
                        aq[s % 3][mi], bfr[nj], acc[mi][nj], 0, 0, 0);
        }
    }

    // Epilogue: C/D 32x32 layout col=lane&31 (pos), row=(rg&3)+8*(rg>>2)+4*half (oc).
    const float bv = bias[0];
    const int hout = h0 + prow;
    const int oc_base = ocb + oc_rel;
    #pragma unroll
    for (int nj = 0; nj < 2; ++nj) {
        int pw = nj * 32 + l31;
        if (pw < 56) {
            #pragma unroll
            for (int mi = 0; mi < 2; ++mi) {
                #pragma unroll
                for (int rg = 0; rg < 16; ++rg) {
                    int oc = oc_base + mi * 32 + (rg & 3) + ((rg >> 2) << 3) + half * 4;
                    out[(size_t)(nb * COUT + oc) * NPIX + hout * HW + pw] = acc[mi][nj][rg] + bv;
                }
            }
        }
    }
}

extern "C" void kernel_launch(void* const* d_in, const int* in_sizes, int n_in,
                              void* d_out, int out_size, void* d_ws, size_t ws_size,
                              hipStream_t stream) {
    const float* x    = (const float*)d_in[0];
    const float* Kw   = (const float*)d_in[1];
    const float* bias = (const float*)d_in[2];
    float* out = (float*)d_out;
    __bf16* W2 = (__bf16*)d_ws;   // needs 589824 bytes of workspace

    wt_transform_kernel<<<dim3(1152), dim3(256), 0, stream>>>(Kw, W2);
    conv_kernel<<<dim3(32 * 14, 2), dim3(512), 0, stream>>>(x, W2, bias, out);
}

// Round 6
// 192.480 us; speedup vs baseline: 1.0668x; 1.0668x over previous
//
#include <hip/hip_runtime.h>

typedef __bf16 bf16x8 __attribute__((ext_vector_type(8)));
typedef float  floatx16 __attribute__((ext_vector_type(16)));

#define HW   56
#define NPIX 3136
#define CIN  128
#define COUT 256

#define AS_GLOBAL __attribute__((address_space(1)))
#define AS_LDS    __attribute__((address_space(3)))

// W2 layout: [cc(4)][tap(9)][cg(4)][oc(256)][j(8)], bf16. 576 KB of d_ws.
__global__ __launch_bounds__(256) void wt_transform_kernel(
        const float* __restrict__ Kw, __bf16* __restrict__ W2) {
    int idx = blockIdx.x * 256 + threadIdx.x;     // coalesced write
    int j     = idx & 7;
    int oc    = (idx >> 3) & 255;
    int cg    = (idx >> 11) & 3;
    int tapcc = idx >> 13;                        // cc*9 + tap
    int tap   = tapcc % 9;
    int cc    = tapcc / 9;
    int c = cc * 32 + cg * 8 + j;
    W2[idx] = (__bf16)Kw[oc * 1152 + c * 9 + tap];
}

// Xs: [row(6)][wp(66)][slot(40)] bf16; slots 0..31 = ci (cg*8+j), 32..39 pad.
// Stride 40 elems = 80 B: bank-base advances 20 banks/wp -> conflict-free b128.
__device__ __forceinline__ int xs_idx(int row, int wp, int cg) {
    return row * 2640 + wp * 40 + cg * 8;
}

// R8: R6 (A via global_load_lds DMA — the proven 91 us base; per-wave A pulls
// are the 105-us-family separator, confirmed by R7's failure) with the tap
// pipeline batched into GROUPS OF 3 taps, double-buffered 2x24 KB:
//   stage+g0,g1 DMA -> barrier -> compute g0 -> barrier -> DMA g2 ->
//   compute g1 (g2 hides under 24 MFMAs) -> vmcnt(0)+barrier ->
//   prefetch next-cc g1 -> compute g2.
// Barriers/cc: 11 -> 4 (44 -> 16 full 16-wave convoys per block); DMA batches
// of 3 amortize L2 latency. Occupancy is register-capped (60 VGPR + 64 AGPR
// ~ 124 unified -> 4 waves/SIMD), so LDS growth to ~80 KB costs nothing.
// T5 setprio around MFMA clusters (phase-split structure now exists).
__global__ __launch_bounds__(512, 4) void conv_kernel(
        const float* __restrict__ x, const __bf16* __restrict__ W2,
        const float* __restrict__ bias, float* __restrict__ out) {
    __shared__ __align__(16) __bf16 Xs[6 * 2640];        // 31.7 KB
    __shared__ __align__(16) __bf16 Abuf[2][3 * 4096];   // 2 x 24 KB tap groups

    const int t    = threadIdx.x;
    const int nb   = blockIdx.x / 14;
    const int ht   = blockIdx.x % 14;
    const int h0   = ht * 4;
    const int ocb  = blockIdx.y * 128;

    const int wid  = t >> 6;          // 0..7
    const int lane = t & 63;
    const int half = lane >> 5;
    const int l31  = lane & 31;

    const int oc_rel = (wid & 1) * 64;          // wave's 64-oc slice within block
    const int prow   = wid >> 1;                // wave's output row (0..3)
    const int aocc   = (oc_rel + l31) * 8;      // A_lds elem base for this lane

    floatx16 acc[2][2];
    #pragma unroll
    for (int mi = 0; mi < 2; ++mi)
        #pragma unroll
        for (int nj = 0; nj < 2; ++nj)
            #pragma unroll
            for (int k = 0; k < 16; ++k)
                acc[mi][nj][k] = 0.f;

    // Zero halo columns wp==0 and wp in [57,66): 6 rows x 10 wp x 4 cg = 240.
    if (t < 240) {
        int cg   = t & 3;
        int rest = t >> 2;            // 0..59
        int row  = rest / 10;
        int zw   = rest % 10;
        int wp   = (zw == 0) ? 0 : (56 + zw);
        *(int4*)&Xs[xs_idx(row, wp, cg)] = make_int4(0, 0, 0, 0);
    }

    // DMA one 8 KB W2 tap-slice -> Abuf[buf] slot. One global_load_lds_dwordx4
    // per thread: t covers cg = t>>7, oc' = t&127, 8 j-elems (16 B). LDS dest
    // linear t*16 (wave-uniform base + lane*size — the HW-required pattern).
    auto dma_a = [&](int cc, int tap, int buf, int slot) {
        const __bf16* src = W2 + (size_t)(cc * 9 + tap) * 8192
                          + (t >> 7) * 2048 + (size_t)(ocb + (t & 127)) * 8;
        __builtin_amdgcn_global_load_lds(
            (const AS_GLOBAL unsigned*)(const void*)src,
            (AS_LDS unsigned*)(void*)&Abuf[buf][slot * 4096 + t * 8], 16, 0, 0);
    };

    // Compute 3 taps of group g (input row prow+g, taps s=0..2) from Abuf[b].
    auto compute_group = [&](int g, int b) {
        __builtin_amdgcn_s_setprio(1);
        #pragma unroll
        for (int tp = 0; tp < 3; ++tp) {
            const __bf16* At = &Abuf[b][tp * 4096];
            #pragma unroll
            for (int kc = 0; kc < 2; ++kc) {
                bf16x8 afr[2];
                #pragma unroll
                for (int mi = 0; mi < 2; ++mi)
                    afr[mi] = *(const bf16x8*)&At[(kc * 2 + half) * 1024 + aocc + mi * 256];
                bf16x8 bfr[2];
                #pragma unroll
                for (int nj = 0; nj < 2; ++nj)
                    bfr[nj] = *(const bf16x8*)&Xs[xs_idx(prow + g, nj * 32 + l31 + tp,
                                                         kc * 2 + half)];
                #pragma unroll
                for (int mi = 0; mi < 2; ++mi)
                    #pragma unroll
                    for (int nj = 0; nj < 2; ++nj)
                        acc[mi][nj] = __builtin_amdgcn_mfma_f32_32x32x16_bf16(
                            afr[mi], bfr[nj], acc[mi][nj], 0, 0, 0);
            }
        }
        __builtin_amdgcn_s_setprio(0);
    };

    // Staging map: t -> (w = t&63, cg = (t>>6)&3, rowgroup = t>>8).
    const int  sw     = t & 63;
    const int  sgr    = t >> 6;       // 0..7
    const int  sg     = sgr & 3;      // cg, uniform per wave -> clean b128 writes
    const int  rg2    = sgr >> 2;     // 0/1 row-group
    const bool wvalid = sw < 56;

    for (int cc = 0; cc < 4; ++cc) {
        __syncthreads();              // (1) Xs + Abuf[0] safe; drains prev vmcnt
        // Group-0 DMA (taps 0-2) -> buf0; hidden under x staging. Group-1 was
        // prefetched at the end of the previous cc (or here on cc==0).
        #pragma unroll
        for (int tp = 0; tp < 3; ++tp) dma_a(cc, tp, 0, tp);
        if (cc == 0) {
            #pragma unroll
            for (int tp = 0; tp < 3; ++tp) dma_a(0, 3 + tp, 1, tp);
        }
        #pragma unroll
        for (int p = 0; p < 3; ++p) {
            int row = rg2 * 3 + p;    // rows 0..2 / 3..5
            int hin = h0 - 1 + row;
            bf16x8 v;
            #pragma unroll
            for (int j = 0; j < 8; ++j) v[j] = (__bf16)0.f;
            if (wvalid && (unsigned)hin < 56u) {
                const float* src = x + (size_t)(nb * CIN + cc * 32 + sg * 8) * NPIX
                                     + hin * HW + sw;
                #pragma unroll
                for (int j = 0; j < 8; ++j)
                    v[j] = (__bf16)src[j * NPIX];   // coalesced across lanes
            }
            if (wvalid)
                *(bf16x8*)&Xs[xs_idx(row, 1 + sw, sg)] = v;   // one ds_write_b128
        }
        __syncthreads();              // (2) drains staging AND g0/g1 DMAs

        compute_group(0, 0);          // taps 0-2 from buf0

        __builtin_amdgcn_s_barrier(); // (3) all waves done reading buf0
        #pragma unroll
        for (int tp = 0; tp < 3; ++tp) dma_a(cc, 6 + tp, 0, tp);  // g2 -> buf0

        compute_group(1, 1);          // taps 3-5 from buf1; g2 DMA hides here

        asm volatile("s_waitcnt vmcnt(0)" ::: "memory");  // own g2 pieces done
        __builtin_amdgcn_s_barrier(); // (4) all waves' g2 visible; buf1 free
        if (cc < 3) {                 // prefetch next cc's group-1 -> buf1
            #pragma unroll
            for (int tp = 0; tp < 3; ++tp) dma_a(cc + 1, 3 + tp, 1, tp);
        }

        compute_group(2, 0);          // taps 6-8 from buf0
    }

    // Epilogue: C/D 32x32 layout col=lane&31 (pos), row=(rg&3)+8*(rg>>2)+4*half (oc).
    const float bv = bias[0];
    const int hout = h0 + prow;
    const int oc_base = ocb + oc_rel;
    #pragma unroll
    for (int nj = 0; nj < 2; ++nj) {
        int pw = nj * 32 + l31;
        if (pw < 56) {
            #pragma unroll
            for (int mi = 0; mi < 2; ++mi) {
                #pragma unroll
                for (int rg = 0; rg < 16; ++rg) {
                    int oc = oc_base + mi * 32 + (rg & 3) + ((rg >> 2) << 3) + half * 4;
                    out[(size_t)(nb * COUT + oc) * NPIX + hout * HW + pw] = acc[mi][nj][rg] + bv;
                }
            }
        }
    }
}

extern "C" void kernel_launch(void* const* d_in, const int* in_sizes, int n_in,
                              void* d_out, int out_size, void* d_ws, size_t ws_size,
                              hipStream_t stream) {
    const float* x    = (const float*)d_in[0];
    const float* Kw   = (const float*)d_in[1];
    const float* bias = (const float*)d_in[2];
    float* out = (float*)d_out;
    __bf16* W2 = (__bf16*)d_ws;   // needs 589824 bytes of workspace

    wt_transform_kernel<<<dim3(1152), dim3(256), 0, stream>>>(Kw, W2);
    conv_kernel<<<dim3(32 * 14, 2), dim3(512), 0, stream>>>(x, W2, bias, out);
}